// Round 1
// baseline (74.742 us; speedup 1.0000x reference)
//
#include <hip/hip_runtime.h>

#define BLOCK 256
#define NBLK  512

// Kernel 1: grid-stride over events; per-thread accumulate, wave + LDS
// reduce, one float2 partial per block into d_ws.
__global__ __launch_bounds__(BLOCK) void nd_partial_kernel(
    const float* __restrict__ data,   // [E,3] row-major: i, j, t
    const float* __restrict__ beta,   // [1]
    const float* __restrict__ z0,     // [N,2]
    float* __restrict__ partials,     // [NBLK*2]
    int E)
{
    const float b = beta[0];
    float s_log = 0.0f;   // sum of (beta - d)
    float s_exp = 0.0f;   // sum of exp(beta - d)

    int tid    = blockIdx.x * BLOCK + threadIdx.x;
    int stride = gridDim.x * BLOCK;
    for (int e = tid; e < E; e += stride) {
        int i = (int)data[3 * e + 0];
        int j = (int)data[3 * e + 1];
        float xi = z0[2 * i + 0];
        float yi = z0[2 * i + 1];
        float xj = z0[2 * j + 0];
        float yj = z0[2 * j + 1];
        float dx = xi - xj;
        float dy = yi - yj;
        float d  = dx * dx + dy * dy;   // == sq[i]+sq[j]-2*dot, exactly in math
        float li = b - d;
        s_log += li;
        s_exp += __expf(li);
    }

    // wave (64-lane) butterfly reduce
    for (int off = 32; off > 0; off >>= 1) {
        s_log += __shfl_down(s_log, off, 64);
        s_exp += __shfl_down(s_exp, off, 64);
    }

    __shared__ float lds1[BLOCK / 64];
    __shared__ float lds2[BLOCK / 64];
    int lane = threadIdx.x & 63;
    int wave = threadIdx.x >> 6;
    if (lane == 0) { lds1[wave] = s_log; lds2[wave] = s_exp; }
    __syncthreads();
    if (threadIdx.x == 0) {
        float t1 = 0.0f, t2 = 0.0f;
        #pragma unroll
        for (int w = 0; w < BLOCK / 64; ++w) { t1 += lds1[w]; t2 += lds2[w]; }
        partials[2 * blockIdx.x + 0] = t1;
        partials[2 * blockIdx.x + 1] = t2;
    }
}

// Kernel 2: single block reduces the NBLK partials; out = non_event - event.
__global__ __launch_bounds__(256) void nd_final_kernel(
    const float* __restrict__ partials,
    float* __restrict__ out,
    int nblk)
{
    float s1 = 0.0f, s2 = 0.0f;
    for (int idx = threadIdx.x; idx < nblk; idx += 256) {
        s1 += partials[2 * idx + 0];
        s2 += partials[2 * idx + 1];
    }
    for (int off = 32; off > 0; off >>= 1) {
        s1 += __shfl_down(s1, off, 64);
        s2 += __shfl_down(s2, off, 64);
    }
    __shared__ float lds1[4];
    __shared__ float lds2[4];
    int lane = threadIdx.x & 63;
    int wave = threadIdx.x >> 6;
    if (lane == 0) { lds1[wave] = s1; lds2[wave] = s2; }
    __syncthreads();
    if (threadIdx.x == 0) {
        float t1 = 0.0f, t2 = 0.0f;
        #pragma unroll
        for (int w = 0; w < 4; ++w) { t1 += lds1[w]; t2 += lds2[w]; }
        // log_likelihood = event - non_event; return -log_likelihood
        out[0] = t2 - t1;
    }
}

extern "C" void kernel_launch(void* const* d_in, const int* in_sizes, int n_in,
                              void* d_out, int out_size, void* d_ws, size_t ws_size,
                              hipStream_t stream) {
    // setup_inputs order: data, t0, tn, beta, z0
    const float* data = (const float*)d_in[0];
    const float* beta = (const float*)d_in[3];
    const float* z0   = (const float*)d_in[4];
    float* out        = (float*)d_out;
    float* partials   = (float*)d_ws;   // NBLK * 2 floats = 4 KB

    int E = in_sizes[0] / 3;

    nd_partial_kernel<<<NBLK, BLOCK, 0, stream>>>(data, beta, z0, partials, E);
    nd_final_kernel<<<1, 256, 0, stream>>>(partials, out, NBLK);
}